// Round 7
// baseline (1179.441 us; speedup 1.0000x reference)
//
#include <hip/hip_runtime.h>
#include <hip/hip_bf16.h>

#define T_TOK 2048
#define D_HID 2048
#define F_INT 1408
#define N_EXP 32
#define TOPK 6
#define NJOBS 34
#define SH_BASE 12288          // routed rows always sum to T_TOK*TOPK = 12288
#define ROWS_TOTAL 16384       // + 2*2048 shared
#define MAXT_GU 96             // sum ceil(cnt/256) <= 80 routed + 16 shared
#define GU_NBN 22              // 1408 / 64
#define MAXT_DN 159            // sum ceil(cnt/128) <= 127 routed + 32 shared
#define LDSW 40                // LDS row stride in bf16 (80 B): 20-bank/row rotation

typedef __bf16 bf16;
typedef __bf16 bf16x4 __attribute__((ext_vector_type(4)));
typedef __bf16 bf16x8 __attribute__((ext_vector_type(8)));
typedef float f32x4 __attribute__((ext_vector_type(4)));

#define BAR() asm volatile("s_waitcnt lgkmcnt(0)\n\ts_barrier" ::: "memory")

// 16B-granule XOR swizzle; all write/read classes verified per-instruction at
// the 32-bank floor (b128 frag reads, b128 A-copy writes, b64 transposed B-writes).
__device__ __forceinline__ int swz16(int r, int k) {
    return r * LDSW + (((k >> 3) ^ ((r >> 3) & 3)) << 3) + (k & 7);
}

// gateup tiles: job -> m0 OUTER -> n0 inner (n-siblings share A-tile in L2),
// m204 bijective XCD chunking. BM=256, BN=64.
__device__ __forceinline__ int decode_gu(const int* __restrict__ counts, int bid,
                                         int& job, int& n0, int& m0) {
    int total = 0;
    for (int j = 0; j < NJOBS; ++j) {
        int c = (j < N_EXP) ? counts[j] : T_TOK;
        total += ((c + 255) >> 8) * GU_NBN;
    }
    if (bid >= total) return 0;
    int q = total >> 3, r = total & 7, x = bid & 7, o = bid >> 3;
    int L = (x < r ? x * (q + 1) : r * (q + 1) + (x - r) * q) + o;
    int acc = 0;
    for (int j = 0; j < NJOBS; ++j) {
        int c = (j < N_EXP) ? counts[j] : T_TOK;
        int tc = (c + 255) >> 8;
        int b = tc * GU_NBN;
        if (L < acc + b) {
            int rem = L - acc;
            job = j;
            m0 = (rem / GU_NBN) << 8;     // m0 outer
            n0 = (rem % GU_NBN) << 6;     // n0 inner: A-sharing siblings adjacent
            return 1;
        }
        acc += b;
    }
    return 0;
}

// down tiles: job -> n0 outer -> m0 inner (B-panel sharing via L2). BM=128, BN=128.
__device__ __forceinline__ int decode_dn(const int* __restrict__ counts, int bid,
                                         int& job, int& n0, int& m0) {
    const int NBN = D_HID / 128;
    int total = 0;
    for (int j = 0; j < NJOBS; ++j) {
        int c = (j < N_EXP) ? counts[j] : T_TOK;
        total += ((c + 127) >> 7) * NBN;
    }
    if (bid >= total) return 0;
    int q = total >> 3, r = total & 7, x = bid & 7, o = bid >> 3;
    int L = (x < r ? x * (q + 1) : r * (q + 1) + (x - r) * q) + o;
    int acc = 0;
    for (int j = 0; j < NJOBS; ++j) {
        int c = (j < N_EXP) ? counts[j] : T_TOK;
        int tc = (c + 127) >> 7;
        int b = tc * NBN;
        if (L < acc + b) {
            int rem = L - acc;
            int n0i = rem / tc;
            job = j;
            n0 = n0i << 7;
            m0 = (rem - n0i * tc) << 7;
            return 1;
        }
        acc += b;
    }
    return 0;
}

// ---------------- X fp32 -> bf16 (one cheap pass) ----------------
__global__ __launch_bounds__(256) void k_xcvt(const float* __restrict__ x,
                                              bf16* __restrict__ xb) {
    int i = blockIdx.x * 2048 + threadIdx.x * 8;
    float4 f0 = *(const float4*)(x + i);
    float4 f1 = *(const float4*)(x + i + 4);
    bf16x8 v = {(bf16)f0.x, (bf16)f0.y, (bf16)f0.z, (bf16)f0.w,
                (bf16)f1.x, (bf16)f1.y, (bf16)f1.z, (bf16)f1.w};
    *(bf16x8*)(xb + i) = v;
}

// ---------------- router ----------------
__global__ __launch_bounds__(256) void k_router(const float* __restrict__ x,
                                                const float* __restrict__ wr,
                                                int* __restrict__ counts,
                                                int* __restrict__ tok_e,
                                                float* __restrict__ tok_w) {
    int t = blockIdx.x;
    int tid = threadIdx.x;
    __shared__ float xs[D_HID];
    __shared__ float part[8][32];
    __shared__ float probs[N_EXP];

    const float4* xsrc = (const float4*)(x + (size_t)t * D_HID);
    float4* xdst = (float4*)xs;
    for (int i = tid; i < D_HID / 4; i += 256) xdst[i] = xsrc[i];
    __syncthreads();

    int e = tid & 31, c = tid >> 5;
    float p = 0.f;
    const float* wp = wr + e;
    #pragma unroll 8
    for (int h = c * 256; h < c * 256 + 256; ++h) p += xs[h] * wp[h * 32];
    part[c][e] = p;
    __syncthreads();

    if (tid < 32) {
        float l = 0.f;
        #pragma unroll
        for (int cc = 0; cc < 8; ++cc) l += part[cc][tid];
        float m = l;
        for (int off = 16; off; off >>= 1) m = fmaxf(m, __shfl_xor(m, off));
        float ex = __expf(l - m);
        float s = ex;
        for (int off = 16; off; off >>= 1) s += __shfl_xor(s, off);
        probs[tid] = ex / s;
    }
    __syncthreads();

    if (tid == 0) {
        unsigned used = 0;
        int ids[TOPK]; float wsv[TOPK]; float wsum = 0.f;
        for (int k = 0; k < TOPK; ++k) {
            int best = 0; float bv = -1.f;
            for (int ee = 0; ee < N_EXP; ++ee)
                if (!((used >> ee) & 1u) && probs[ee] > bv) { bv = probs[ee]; best = ee; }
            used |= 1u << best;
            ids[k] = best; wsv[k] = bv; wsum += bv;
        }
        float inv = 1.f / wsum;
        for (int k = 0; k < TOPK; ++k) {
            tok_e[t * TOPK + k] = ids[k];
            tok_w[t * TOPK + k] = wsv[k] * inv;
            atomicAdd(&counts[ids[k]], 1);
        }
    }
}

// ---------------- plan ----------------
__global__ void k_plan(const int* __restrict__ counts, int* __restrict__ offs,
                       int* __restrict__ cursors) {
    int tid = threadIdx.x;
    if (tid < N_EXP) cursors[tid] = 0;
    if (tid == 0) {
        int o = 0;
        offs[0] = 0;
        for (int e2 = 0; e2 < N_EXP; ++e2) { o += counts[e2]; offs[e2 + 1] = o; }
        offs[33] = offs[32] + T_TOK;
        offs[34] = offs[33] + T_TOK;
    }
}

// ---------------- assign ----------------
__global__ __launch_bounds__(256) void k_assign(const int* __restrict__ tok_e,
                                                const int* __restrict__ offs,
                                                int* __restrict__ cursors,
                                                int* __restrict__ slots,
                                                int* __restrict__ rowtok) {
    int t = blockIdx.x * 256 + threadIdx.x;
    #pragma unroll
    for (int k = 0; k < TOPK; ++k) {
        int e = tok_e[t * TOPK + k];
        int pos = atomicAdd(&cursors[e], 1);
        int slot = offs[e] + pos;
        slots[t * TOPK + k] = slot;
        rowtok[slot] = t;
    }
    rowtok[SH_BASE + t] = t;
    rowtok[SH_BASE + T_TOK + t] = t;
}

// ---------------- GEMM1: H = silu(X Wg) * (X Wu) ----------------
// BM=256 x BN=64, BK=32, 512 threads / 8 waves. Wave (wid): matrix = wid&1
// (0:g, 1:u), m-quadrant = wid>>1; wave tile 64x64 of ONE matrix (acc=64 regs).
// Staging roles: wid 0-1 Bg, wid 2-3 Bu, wid 4-7 A (bf16 copy from Xb).
// silu combine via one-time LDS scratch exchange at the end.
__global__ __launch_bounds__(512, 4) void k_gateup(
    const bf16* __restrict__ xb, const float* __restrict__ wg, const float* __restrict__ wu,
    const float* __restrict__ sg, const float* __restrict__ su,
    const int* __restrict__ rowtok, const int* __restrict__ counts, const int* __restrict__ offs,
    bf16* __restrict__ H) {

    int job, n0, m0;
    if (!decode_gu(counts, blockIdx.x, job, n0, m0)) return;
    int cnt = (job < N_EXP) ? counts[job] : T_TOK;
    int base = offs[job];
    const float* Wg = (job < N_EXP) ? wg + (size_t)job * D_HID * F_INT
                                    : sg + (size_t)(job - N_EXP) * D_HID * F_INT;
    const float* Wu = (job < N_EXP) ? wu + (size_t)job * D_HID * F_INT
                                    : su + (size_t)(job - N_EXP) * D_HID * F_INT;

    __shared__ bf16 AsF[2 * 256 * LDSW];   // 40 KB
    __shared__ bf16 BgF[2 * 64 * LDSW];    // 10 KB
    __shared__ bf16 BuF[2 * 64 * LDSW];    // 10 KB

    int tid = threadIdx.x;
    int lane = tid & 63;
    int wid = tid >> 6;
    int mat = wid & 1;                     // 0 = gate, 1 = up
    int wm = (wid >> 1) * 64;              // m-quadrant base

    // ---- staging role ----
    // wid 0-1 -> Bg, wid 2-3 -> Bu: thread (kk 4 k-rows, nn 4 n-cols)
    int bt  = tid & 127;
    int kk  = (bt >> 4) * 4;               // 0..28
    int nn  = (bt & 15) * 4;               // 0..60
    const float* wsrc = ((wid < 2) ? Wg : Wu) + (size_t)kk * F_INT + n0 + nn;
    bf16* bdst = (wid < 2) ? BgF : BuF;
    // wid 4-7 -> A: thread copies one row's 32 k (4 x b128)
    int ar = tid & 255;
    int grow_a = m0 + ar; if (grow_a > cnt - 1) grow_a = cnt - 1;
    const bf16* asrc = xb + (size_t)rowtok[base + grow_a] * D_HID;

    f32x4 acc[4][4];
    f32x4 zero = {0.f, 0.f, 0.f, 0.f};
    #pragma unroll
    for (int i = 0; i < 4; ++i)
        #pragma unroll
        for (int j = 0; j < 4; ++j) acc[i][j] = zero;

    float4 st[4];

    auto LOAD = [&](int k0) {
        if (wid < 4) {
            const float* s0 = wsrc + (size_t)k0 * F_INT;
            st[0] = *(const float4*)s0;
            st[1] = *(const float4*)(s0 + F_INT);
            st[2] = *(const float4*)(s0 + 2 * F_INT);
            st[3] = *(const float4*)(s0 + 3 * F_INT);
        } else {
            const bf16* a0 = asrc + k0;
            st[0] = *(const float4*)(const void*)(a0);
            st[1] = *(const float4*)(const void*)(a0 + 8);
            st[2] = *(const float4*)(const void*)(a0 + 16);
            st[3] = *(const float4*)(const void*)(a0 + 24);
        }
    };

    auto WRITE = [&](int s) {
        if (wid < 4) {
            bf16* bd = bdst + s * (64 * LDSW);
            bf16x4 p0 = {(bf16)st[0].x, (bf16)st[1].x, (bf16)st[2].x, (bf16)st[3].x};
            bf16x4 p1 = {(bf16)st[0].y, (bf16)st[1].y, (bf16)st[2].y, (bf16)st[3].y};
            bf16x4 p2 = {(bf16)st[0].z, (bf16)st[1].z, (bf16)st[2].z, (bf16)st[3].z};
            bf16x4 p3 = {(bf16)st[0].w, (bf16)st[1].w, (bf16)st[2].w, (bf16)st[3].w};
            *(bf16x4*)&bd[swz16(nn + 0, kk)] = p0;
            *(bf16x4*)&bd[swz16(nn + 1, kk)] = p1;
            *(bf16x4*)&bd[swz16(nn + 2, kk)] = p2;
            *(bf16x4*)&bd[swz16(nn + 3, kk)] = p3;
        } else {
            bf16* ad = AsF + s * (256 * LDSW);
            *(float4*)(void*)&ad[swz16(ar, 0)]  = st[0];
            *(float4*)(void*)&ad[swz16(ar, 8)]  = st[1];
            *(float4*)(void*)&ad[swz16(ar, 16)] = st[2];
            *(float4*)(void*)&ad[swz16(ar, 24)] = st[3];
        }
    };

    const int NT = D_HID / 32;
    LOAD(0);
    WRITE(0);
    LOAD(32);
    BAR();

    const bf16* bread = mat ? BuF : BgF;
    for (int kt = 0; kt < NT; ++kt) {
        int cur = kt & 1;
        if (kt + 1 < NT) WRITE(cur ^ 1);
        if (kt + 2 < NT) LOAD((kt + 2) * 32);

        int kgl = (lane >> 4) * 8;
        const bf16* ac = AsF + cur * (256 * LDSW);
        const bf16* bc = bread + cur * (64 * LDSW);
        bf16x8 af[4];
        #pragma unroll
        for (int mf = 0; mf < 4; ++mf)
            af[mf] = *(const bf16x8*)&ac[swz16(wm + mf * 16 + (lane & 15), kgl)];
        #pragma unroll
        for (int nf = 0; nf < 4; ++nf) {
            bf16x8 bfr = *(const bf16x8*)&bc[swz16(nf * 16 + (lane & 15), kgl)];
            #pragma unroll
            for (int mf = 0; mf < 4; ++mf)
                acc[mf][nf] = __builtin_amdgcn_mfma_f32_16x16x32_bf16(af[mf], bfr, acc[mf][nf], 0, 0, 0);
        }
        BAR();
    }

    // ---- combine: u-waves park u in LDS scratch, g-waves compute silu(g)*u ----
    bf16* uscr = AsF;   // 256x64 bf16 = 32 KB scratch (bank-XOR'd cols)
    if (mat == 1) {
        #pragma unroll
        for (int mf = 0; mf < 4; ++mf)
            #pragma unroll
            for (int nf = 0; nf < 4; ++nf)
                #pragma unroll
                for (int r = 0; r < 4; ++r) {
                    int row = mf * 16 + (lane >> 4) * 4 + r;
                    int col = nf * 16 + (lane & 15);
                    uscr[(wm + row) * 64 + (col ^ ((row & 7) << 3))] = (bf16)acc[mf][nf][r];
                }
    }
    __syncthreads();
    if (mat == 0) {
        #pragma unroll
        for (int mf = 0; mf < 4; ++mf)
            #pragma unroll
            for (int nf = 0; nf < 4; ++nf)
                #pragma unroll
                for (int r = 0; r < 4; ++r) {
                    int row = mf * 16 + (lane >> 4) * 4 + r;
                    int col = nf * 16 + (lane & 15);
                    int grow = m0 + wm + row;
                    if (grow < cnt) {
                        float u = (float)uscr[(wm + row) * 64 + (col ^ ((row & 7) << 3))];
                        float g = acc[mf][nf][r];
                        float h = g * u / (1.f + __expf(-g));
                        H[(size_t)(base + grow) * F_INT + n0 + col] = (bf16)h;
                    }
                }
    }
}

// ---------------- GEMM2: P = H Wd ----------------
// Tile 128x128, BK=32, 4 waves of 64x64, dbuf LDS, 1 barrier/iter. (unchanged)
__global__ __launch_bounds__(256, 3) void k_down(
    const bf16* __restrict__ H, const float* __restrict__ wd, const float* __restrict__ sd,
    const int* __restrict__ counts, const int* __restrict__ offs,
    bf16* __restrict__ P) {

    int job, n0, m0;
    if (!decode_dn(counts, blockIdx.x, job, n0, m0)) return;
    int cnt = (job < N_EXP) ? counts[job] : T_TOK;
    int base = offs[job];
    const float* Wd = (job < N_EXP) ? wd + (size_t)job * F_INT * D_HID
                                    : sd + (size_t)(job - N_EXP) * F_INT * D_HID;

    __shared__ bf16 As[2][128 * LDSW];
    __shared__ bf16 Bs[2][128 * LDSW];

    int tid = threadIdx.x;
    int lane = tid & 63;
    int wid = tid >> 6;
    int wm = (wid >> 1) * 64;
    int wn = (wid & 1) * 64;

    int ar = tid >> 1;
    int akg2 = (tid & 1) * 2;
    int grow_a = m0 + ar; if (grow_a > cnt - 1) grow_a = cnt - 1;
    const bf16* asrc = H + (size_t)(base + grow_a) * F_INT + akg2 * 8;

    int k4 = (tid >> 5) * 4;
    int nn = (tid & 31) * 4;
    const float* bsrc = Wd + (size_t)k4 * D_HID + n0 + nn;

    f32x4 acc[4][4];
    f32x4 zero = {0.f, 0.f, 0.f, 0.f};
    #pragma unroll
    for (int i = 0; i < 4; ++i)
        #pragma unroll
        for (int j = 0; j < 4; ++j) acc[i][j] = zero;

    bf16x8 h_r[2];
    float4 b_r[4];

    auto LOAD = [&](int k0) {
        h_r[0] = *(const bf16x8*)(asrc + k0);
        h_r[1] = *(const bf16x8*)(asrc + k0 + 8);
        const float* b0 = bsrc + (size_t)k0 * D_HID;
        b_r[0] = *(const float4*)b0;
        b_r[1] = *(const float4*)(b0 + D_HID);
        b_r[2] = *(const float4*)(b0 + 2 * D_HID);
        b_r[3] = *(const float4*)(b0 + 3 * D_HID);
    };

    auto WRITE = [&](int s) {
        *(bf16x8*)&As[s][swz16(ar, akg2 * 8)] = h_r[0];
        *(bf16x8*)&As[s][swz16(ar, (akg2 + 1) * 8)] = h_r[1];
        bf16x4 p0 = {(bf16)b_r[0].x, (bf16)b_r[1].x, (bf16)b_r[2].x, (bf16)b_r[3].x};
        bf16x4 p1 = {(bf16)b_r[0].y, (bf16)b_r[1].y, (bf16)b_r[2].y, (bf16)b_r[3].y};
        bf16x4 p2 = {(bf16)b_r[0].z, (bf16)b_r[1].z, (bf16)b_r[2].z, (bf16)b_r[3].z};
        bf16x4 p3 = {(bf16)b_r[0].w, (bf16)b_r[1].w, (bf16)b_r[2].w, (bf16)b_r[3].w};
        *(bf16x4*)&Bs[s][swz16(nn + 0, k4)] = p0;
        *(bf16x4*)&Bs[s][swz16(nn + 1, k4)] = p1;
        *(bf16x4*)&Bs[s][swz16(nn + 2, k4)] = p2;
        *(bf16x4*)&Bs[s][swz16(nn + 3, k4)] = p3;
    };

    const int NT = F_INT / 32;
    LOAD(0);
    WRITE(0);
    LOAD(32);
    BAR();

    for (int kt = 0; kt < NT; ++kt) {
        int cur = kt & 1;
        if (kt + 1 < NT) WRITE(cur ^ 1);
        if (kt + 2 < NT) LOAD((kt + 2) * 32);

        int kgl = (lane >> 4) * 8;
        bf16x8 af[4];
        #pragma unroll
        for (int mf = 0; mf < 4; ++mf)
            af[mf] = *(const bf16x8*)&As[cur][swz16(wm + mf * 16 + (lane & 15), kgl)];
        #pragma unroll
        for (int nf = 0; nf < 4; ++nf) {
            int rn = wn + nf * 16 + (lane & 15);
            bf16x8 bfr = *(const bf16x8*)&Bs[cur][swz16(rn, kgl)];
            #pragma unroll
            for (int mf = 0; mf < 4; ++mf)
                acc[mf][nf] = __builtin_amdgcn_mfma_f32_16x16x32_bf16(af[mf], bfr, acc[mf][nf], 0, 0, 0);
        }
        BAR();
    }

    #pragma unroll
    for (int mf = 0; mf < 4; ++mf) {
        #pragma unroll
        for (int nf = 0; nf < 4; ++nf) {
            int col = n0 + wn + nf * 16 + (lane & 15);
            #pragma unroll
            for (int r = 0; r < 4; ++r) {
                int grow = m0 + wm + mf * 16 + (lane >> 4) * 4 + r;
                if (grow < cnt)
                    P[(size_t)(base + grow) * D_HID + col] = (bf16)acc[mf][nf][r];
            }
        }
    }
}

// ---------------- combine ----------------
__global__ __launch_bounds__(256) void k_combine(const bf16* __restrict__ P,
                                                 const int* __restrict__ slots,
                                                 const float* __restrict__ tok_w,
                                                 float* __restrict__ out) {
    int t = blockIdx.x;
    int tid = threadIdx.x;
    __shared__ int ss[TOPK];
    __shared__ float ww[TOPK];
    if (tid < TOPK) { ss[tid] = slots[t * TOPK + tid]; ww[tid] = tok_w[t * TOPK + tid]; }
    __syncthreads();
    int c0 = tid * 8;
    float acc[8];
    {
        bf16x8 v0 = *(const bf16x8*)(P + (size_t)(SH_BASE + t) * D_HID + c0);
        bf16x8 v1 = *(const bf16x8*)(P + (size_t)(SH_BASE + T_TOK + t) * D_HID + c0);
        #pragma unroll
        for (int i = 0; i < 8; ++i) acc[i] = (float)v0[i] + (float)v1[i];
    }
    #pragma unroll
    for (int k = 0; k < TOPK; ++k) {
        bf16x8 v = *(const bf16x8*)(P + (size_t)ss[k] * D_HID + c0);
        float w = ww[k];
        #pragma unroll
        for (int i = 0; i < 8; ++i) acc[i] += w * (float)v[i];
    }
    float4 o0 = {acc[0], acc[1], acc[2], acc[3]};
    float4 o1 = {acc[4], acc[5], acc[6], acc[7]};
    *(float4*)(out + (size_t)t * D_HID + c0) = o0;
    *(float4*)(out + (size_t)t * D_HID + c0 + 4) = o1;
}

extern "C" void kernel_launch(void* const* d_in, const int* in_sizes, int n_in,
                              void* d_out, int out_size, void* d_ws, size_t ws_size,
                              hipStream_t stream) {
    const float* x  = (const float*)d_in[0];
    const float* wr = (const float*)d_in[1];
    const float* wg = (const float*)d_in[2];
    const float* wu = (const float*)d_in[3];
    const float* wd = (const float*)d_in[4];
    const float* sg = (const float*)d_in[5];
    const float* su = (const float*)d_in[6];
    const float* sd = (const float*)d_in[7];
    float* out = (float*)d_out;

    char* w = (char*)d_ws;
    int*   counts   = (int*)(w + 0);        // 32 ints
    int*   cursors  = (int*)(w + 256);      // 32 ints
    int*   offs     = (int*)(w + 512);      // 35 ints
    int*   tok_e    = (int*)(w + 8192);                 // 12288 ints
    float* tok_w    = (float*)(w + 8192 + 49152);       // 12288 floats
    int*   slots    = (int*)(w + 8192 + 2 * 49152);     // 12288 ints
    int*   rowtok   = (int*)(w + 8192 + 3 * 49152);     // 16384 ints
    bf16*  H        = (bf16*)(w + 262144);                                  // 16384 x 1408 bf16
    bf16*  P        = (bf16*)(w + 262144 + (size_t)ROWS_TOTAL * F_INT * 2); // 16384 x 2048 bf16
    bf16*  Xb       = (bf16*)(w + 262144 + (size_t)ROWS_TOTAL * F_INT * 2
                                        + (size_t)ROWS_TOTAL * D_HID * 2);  // 2048 x 2048 bf16

    hipMemsetAsync(counts, 0, 128, stream);
    k_xcvt<<<T_TOK * D_HID / 2048, 256, 0, stream>>>(x, Xb);
    k_router<<<T_TOK, 256, 0, stream>>>(x, wr, counts, tok_e, tok_w);
    k_plan<<<1, 64, 0, stream>>>(counts, offs, cursors);
    k_assign<<<T_TOK / 256, 256, 0, stream>>>(tok_e, offs, cursors, slots, rowtok);
    k_gateup<<<MAXT_GU * GU_NBN, 512, 0, stream>>>(
        Xb, wg, wu, sg, su, rowtok, counts, offs, H);
    k_down<<<MAXT_DN * (D_HID / 128), 256, 0, stream>>>(
        H, wd, sd, counts, offs, P);
    k_combine<<<T_TOK, 256, 0, stream>>>(P, slots, tok_w, out);
}

// Round 8
// 888.554 us; speedup vs baseline: 1.3274x; 1.3274x over previous
//
#include <hip/hip_runtime.h>
#include <hip/hip_bf16.h>

#define T_TOK 2048
#define D_HID 2048
#define F_INT 1408
#define N_EXP 32
#define TOPK 6
#define NJOBS 34
#define SH_BASE 12288          // routed rows always sum to T_TOK*TOPK = 12288
#define ROWS_TOTAL 16384       // + 2*2048 shared
#define MAXT_GU 159            // sum ceil(cnt/128) <= 127 routed + 32 shared
#define GU_NBN 22              // 1408 / 64
#define MAXT_DN 159
#define LDSW 40                // LDS row stride in bf16 (80 B)

typedef __bf16 bf16;
typedef __bf16 bf16x4 __attribute__((ext_vector_type(4)));
typedef __bf16 bf16x8 __attribute__((ext_vector_type(8)));
typedef float f32x4 __attribute__((ext_vector_type(4)));

#define BAR() asm volatile("s_waitcnt lgkmcnt(0)\n\ts_barrier" ::: "memory")

// 16B-granule XOR swizzle, row stride 80 B. Granule XOR includes BOTH (r>>3)
// and (r>>5) bits so 32-row-strided transposed writes don't alias (R7 bug):
// B-writes <=2-way (free), A-writes & b128 frag reads at bank floor.
__device__ __forceinline__ int swz16(int r, int k) {
    return r * LDSW + ((((k >> 3) ^ ((r >> 3) & 3) ^ ((r >> 5) & 3)) & 3) << 3) + (k & 7);
}

// bid -> (job, n0, m0); job -> n0 outer -> m0 inner (panel-sharing m-siblings
// adjacent -> same XCD L2), m204 bijective XCD chunking.
__device__ __forceinline__ int decode_tile(const int* __restrict__ counts, int bid,
                                           int NBN, int MSH, int NSH,
                                           int& job, int& n0, int& m0) {
    int total = 0;
    for (int j = 0; j < NJOBS; ++j) {
        int c = (j < N_EXP) ? counts[j] : T_TOK;
        total += ((c + (1 << MSH) - 1) >> MSH) * NBN;
    }
    if (bid >= total) return 0;
    int q = total >> 3, r = total & 7, x = bid & 7, o = bid >> 3;
    int L = (x < r ? x * (q + 1) : r * (q + 1) + (x - r) * q) + o;
    int acc = 0;
    for (int j = 0; j < NJOBS; ++j) {
        int c = (j < N_EXP) ? counts[j] : T_TOK;
        int tc = (c + (1 << MSH) - 1) >> MSH;
        int b = tc * NBN;
        if (L < acc + b) {
            int rem = L - acc;
            int n0i = rem / tc;
            job = j;
            n0 = n0i << NSH;
            m0 = (rem - n0i * tc) << MSH;
            return 1;
        }
        acc += b;
    }
    return 0;
}

// ---------------- X fp32 -> bf16 ----------------
__global__ __launch_bounds__(256) void k_xcvt(const float* __restrict__ x,
                                              bf16* __restrict__ xb) {
    int i = blockIdx.x * 2048 + threadIdx.x * 8;
    float4 f0 = *(const float4*)(x + i);
    float4 f1 = *(const float4*)(x + i + 4);
    bf16x8 v = {(bf16)f0.x, (bf16)f0.y, (bf16)f0.z, (bf16)f0.w,
                (bf16)f1.x, (bf16)f1.y, (bf16)f1.z, (bf16)f1.w};
    *(bf16x8*)(xb + i) = v;
}

// ---------------- router ----------------
__global__ __launch_bounds__(256) void k_router(const float* __restrict__ x,
                                                const float* __restrict__ wr,
                                                int* __restrict__ counts,
                                                int* __restrict__ tok_e,
                                                float* __restrict__ tok_w) {
    int t = blockIdx.x;
    int tid = threadIdx.x;
    __shared__ float xs[D_HID];
    __shared__ float part[8][32];
    __shared__ float probs[N_EXP];

    const float4* xsrc = (const float4*)(x + (size_t)t * D_HID);
    float4* xdst = (float4*)xs;
    for (int i = tid; i < D_HID / 4; i += 256) xdst[i] = xsrc[i];
    __syncthreads();

    int e = tid & 31, c = tid >> 5;
    float p = 0.f;
    const float* wp = wr + e;
    #pragma unroll 8
    for (int h = c * 256; h < c * 256 + 256; ++h) p += xs[h] * wp[h * 32];
    part[c][e] = p;
    __syncthreads();

    if (tid < 32) {
        float l = 0.f;
        #pragma unroll
        for (int cc = 0; cc < 8; ++cc) l += part[cc][tid];
        float m = l;
        for (int off = 16; off; off >>= 1) m = fmaxf(m, __shfl_xor(m, off));
        float ex = __expf(l - m);
        float s = ex;
        for (int off = 16; off; off >>= 1) s += __shfl_xor(s, off);
        probs[tid] = ex / s;
    }
    __syncthreads();

    if (tid == 0) {
        unsigned used = 0;
        int ids[TOPK]; float wsv[TOPK]; float wsum = 0.f;
        for (int k = 0; k < TOPK; ++k) {
            int best = 0; float bv = -1.f;
            for (int ee = 0; ee < N_EXP; ++ee)
                if (!((used >> ee) & 1u) && probs[ee] > bv) { bv = probs[ee]; best = ee; }
            used |= 1u << best;
            ids[k] = best; wsv[k] = bv; wsum += bv;
        }
        float inv = 1.f / wsum;
        for (int k = 0; k < TOPK; ++k) {
            tok_e[t * TOPK + k] = ids[k];
            tok_w[t * TOPK + k] = wsv[k] * inv;
            atomicAdd(&counts[ids[k]], 1);
        }
    }
}

// ---------------- plan ----------------
__global__ void k_plan(const int* __restrict__ counts, int* __restrict__ offs,
                       int* __restrict__ cursors) {
    int tid = threadIdx.x;
    if (tid < N_EXP) cursors[tid] = 0;
    if (tid == 0) {
        int o = 0;
        offs[0] = 0;
        for (int e2 = 0; e2 < N_EXP; ++e2) { o += counts[e2]; offs[e2 + 1] = o; }
        offs[33] = offs[32] + T_TOK;
        offs[34] = offs[33] + T_TOK;
    }
}

// ---------------- assign ----------------
__global__ __launch_bounds__(256) void k_assign(const int* __restrict__ tok_e,
                                                const int* __restrict__ offs,
                                                int* __restrict__ cursors,
                                                int* __restrict__ slots,
                                                int* __restrict__ rowtok) {
    int t = blockIdx.x * 256 + threadIdx.x;
    #pragma unroll
    for (int k = 0; k < TOPK; ++k) {
        int e = tok_e[t * TOPK + k];
        int pos = atomicAdd(&cursors[e], 1);
        int slot = offs[e] + pos;
        slots[t * TOPK + k] = slot;
        rowtok[slot] = t;
    }
    rowtok[SH_BASE + t] = t;
    rowtok[SH_BASE + T_TOK + t] = t;
}

// ---------------- GEMM1: H = silu(X Wg) * (X Wu) ----------------
// BM=128 x BN=64, BK=32, 4 waves, wave tile 64x32 of BOTH matrices (acc=64).
// A: pure bf16 b128 copy from Xb (cheap M growth); B fp32 bytes halved/iter.
__global__ __launch_bounds__(256, 3) void k_gateup(
    const bf16* __restrict__ xb, const float* __restrict__ wg, const float* __restrict__ wu,
    const float* __restrict__ sg, const float* __restrict__ su,
    const int* __restrict__ rowtok, const int* __restrict__ counts, const int* __restrict__ offs,
    bf16* __restrict__ H) {

    int job, n0, m0;
    if (!decode_tile(counts, blockIdx.x, GU_NBN, 7, 6, job, n0, m0)) return;
    int cnt = (job < N_EXP) ? counts[job] : T_TOK;
    int base = offs[job];
    const float* Wg = (job < N_EXP) ? wg + (size_t)job * D_HID * F_INT
                                    : sg + (size_t)(job - N_EXP) * D_HID * F_INT;
    const float* Wu = (job < N_EXP) ? wu + (size_t)job * D_HID * F_INT
                                    : su + (size_t)(job - N_EXP) * D_HID * F_INT;

    __shared__ bf16 As[2][128 * LDSW];
    __shared__ bf16 Bg[2][64 * LDSW];
    __shared__ bf16 Bu[2][64 * LDSW];

    int tid = threadIdx.x;
    int lane = tid & 63;
    int wid = tid >> 6;
    int wm = (wid & 1) * 64;
    int wn = (wid >> 1) * 32;

    // A staging: thread -> row ar, two 8-elem k-granules (bf16 copy)
    int ar = tid >> 1;
    int akg2 = (tid & 1) * 2;
    int grow_a = m0 + ar; if (grow_a > cnt - 1) grow_a = cnt - 1;
    const bf16* asrc = xb + (size_t)rowtok[base + grow_a] * D_HID + akg2 * 8;

    // B staging: thread -> one matrix (t>>7), 4 k-rows x 4 n-cols
    int sub = tid & 127;
    int k4 = (sub & 7) * 4;                 // 0..28
    int nn = (sub >> 3) * 4;                // 0..60
    const float* wsrc = ((tid & 128) ? Wu : Wg) + (size_t)k4 * F_INT + n0 + nn;

    f32x4 accg[4][2], accu[4][2];
    f32x4 zero = {0.f, 0.f, 0.f, 0.f};
    #pragma unroll
    for (int i = 0; i < 4; ++i)
        #pragma unroll
        for (int j = 0; j < 2; ++j) { accg[i][j] = zero; accu[i][j] = zero; }

    bf16x8 a_r[2];
    float4 b_r[4];

    auto LOAD = [&](int k0) {
        a_r[0] = *(const bf16x8*)(asrc + k0);
        a_r[1] = *(const bf16x8*)(asrc + k0 + 8);
        const float* b0 = wsrc + (size_t)k0 * F_INT;
        b_r[0] = *(const float4*)b0;
        b_r[1] = *(const float4*)(b0 + F_INT);
        b_r[2] = *(const float4*)(b0 + 2 * F_INT);
        b_r[3] = *(const float4*)(b0 + 3 * F_INT);
    };

    auto WRITE = [&](int s) {
        *(bf16x8*)&As[s][swz16(ar, akg2 * 8)] = a_r[0];
        *(bf16x8*)&As[s][swz16(ar, (akg2 + 1) * 8)] = a_r[1];
        bf16* bd = (tid & 128) ? Bu[s] : Bg[s];
        bf16x4 p0 = {(bf16)b_r[0].x, (bf16)b_r[1].x, (bf16)b_r[2].x, (bf16)b_r[3].x};
        bf16x4 p1 = {(bf16)b_r[0].y, (bf16)b_r[1].y, (bf16)b_r[2].y, (bf16)b_r[3].y};
        bf16x4 p2 = {(bf16)b_r[0].z, (bf16)b_r[1].z, (bf16)b_r[2].z, (bf16)b_r[3].z};
        bf16x4 p3 = {(bf16)b_r[0].w, (bf16)b_r[1].w, (bf16)b_r[2].w, (bf16)b_r[3].w};
        *(bf16x4*)&bd[swz16(nn + 0, k4)] = p0;
        *(bf16x4*)&bd[swz16(nn + 1, k4)] = p1;
        *(bf16x4*)&bd[swz16(nn + 2, k4)] = p2;
        *(bf16x4*)&bd[swz16(nn + 3, k4)] = p3;
    };

    const int NT = D_HID / 32;
    LOAD(0);
    WRITE(0);
    LOAD(32);
    BAR();

    for (int kt = 0; kt < NT; ++kt) {
        int cur = kt & 1;
        if (kt + 1 < NT) WRITE(cur ^ 1);
        if (kt + 2 < NT) LOAD((kt + 2) * 32);

        int kgl = (lane >> 4) * 8;
        bf16x8 af[4];
        #pragma unroll
        for (int mf = 0; mf < 4; ++mf)
            af[mf] = *(const bf16x8*)&As[cur][swz16(wm + mf * 16 + (lane & 15), kgl)];
        #pragma unroll
        for (int nf = 0; nf < 2; ++nf) {
            int rn = wn + nf * 16 + (lane & 15);
            int o = swz16(rn, kgl);
            bf16x8 bfr = *(const bf16x8*)&Bg[cur][o];
            bf16x8 ufr = *(const bf16x8*)&Bu[cur][o];
            #pragma unroll
            for (int mf = 0; mf < 4; ++mf) {
                accg[mf][nf] = __builtin_amdgcn_mfma_f32_16x16x32_bf16(af[mf], bfr, accg[mf][nf], 0, 0, 0);
                accu[mf][nf] = __builtin_amdgcn_mfma_f32_16x16x32_bf16(af[mf], ufr, accu[mf][nf], 0, 0, 0);
            }
        }
        BAR();
    }

    // epilogue: h = silu(g) * u -> bf16 H (in-register)
    #pragma unroll
    for (int mf = 0; mf < 4; ++mf) {
        #pragma unroll
        for (int nf = 0; nf < 2; ++nf) {
            int col = n0 + wn + nf * 16 + (lane & 15);
            #pragma unroll
            for (int r = 0; r < 4; ++r) {
                int grow = m0 + wm + mf * 16 + (lane >> 4) * 4 + r;
                if (grow < cnt) {
                    float g = accg[mf][nf][r];
                    float u = accu[mf][nf][r];
                    float h = g * u / (1.f + __expf(-g));
                    H[(size_t)(base + grow) * F_INT + col] = (bf16)h;
                }
            }
        }
    }
}

// ---------------- GEMM2: P = H Wd ----------------
// Tile 128x128, BK=32, 4 waves of 64x64, dbuf LDS, 1 barrier/iter.
__global__ __launch_bounds__(256, 3) void k_down(
    const bf16* __restrict__ H, const float* __restrict__ wd, const float* __restrict__ sd,
    const int* __restrict__ counts, const int* __restrict__ offs,
    bf16* __restrict__ P) {

    int job, n0, m0;
    if (!decode_tile(counts, blockIdx.x, D_HID / 128, 7, 7, job, n0, m0)) return;
    int cnt = (job < N_EXP) ? counts[job] : T_TOK;
    int base = offs[job];
    const float* Wd = (job < N_EXP) ? wd + (size_t)job * F_INT * D_HID
                                    : sd + (size_t)(job - N_EXP) * F_INT * D_HID;

    __shared__ bf16 As[2][128 * LDSW];
    __shared__ bf16 Bs[2][128 * LDSW];

    int tid = threadIdx.x;
    int lane = tid & 63;
    int wid = tid >> 6;
    int wm = (wid >> 1) * 64;
    int wn = (wid & 1) * 64;

    int ar = tid >> 1;
    int akg2 = (tid & 1) * 2;
    int grow_a = m0 + ar; if (grow_a > cnt - 1) grow_a = cnt - 1;
    const bf16* asrc = H + (size_t)(base + grow_a) * F_INT + akg2 * 8;

    int k4 = (tid >> 5) * 4;
    int nn = (tid & 31) * 4;
    const float* bsrc = Wd + (size_t)k4 * D_HID + n0 + nn;

    f32x4 acc[4][4];
    f32x4 zero = {0.f, 0.f, 0.f, 0.f};
    #pragma unroll
    for (int i = 0; i < 4; ++i)
        #pragma unroll
        for (int j = 0; j < 4; ++j) acc[i][j] = zero;

    bf16x8 h_r[2];
    float4 b_r[4];

    auto LOAD = [&](int k0) {
        h_r[0] = *(const bf16x8*)(asrc + k0);
        h_r[1] = *(const bf16x8*)(asrc + k0 + 8);
        const float* b0 = bsrc + (size_t)k0 * D_HID;
        b_r[0] = *(const float4*)b0;
        b_r[1] = *(const float4*)(b0 + D_HID);
        b_r[2] = *(const float4*)(b0 + 2 * D_HID);
        b_r[3] = *(const float4*)(b0 + 3 * D_HID);
    };

    auto WRITE = [&](int s) {
        *(bf16x8*)&As[s][swz16(ar, akg2 * 8)] = h_r[0];
        *(bf16x8*)&As[s][swz16(ar, (akg2 + 1) * 8)] = h_r[1];
        bf16x4 p0 = {(bf16)b_r[0].x, (bf16)b_r[1].x, (bf16)b_r[2].x, (bf16)b_r[3].x};
        bf16x4 p1 = {(bf16)b_r[0].y, (bf16)b_r[1].y, (bf16)b_r[2].y, (bf16)b_r[3].y};
        bf16x4 p2 = {(bf16)b_r[0].z, (bf16)b_r[1].z, (bf16)b_r[2].z, (bf16)b_r[3].z};
        bf16x4 p3 = {(bf16)b_r[0].w, (bf16)b_r[1].w, (bf16)b_r[2].w, (bf16)b_r[3].w};
        *(bf16x4*)&Bs[s][swz16(nn + 0, k4)] = p0;
        *(bf16x4*)&Bs[s][swz16(nn + 1, k4)] = p1;
        *(bf16x4*)&Bs[s][swz16(nn + 2, k4)] = p2;
        *(bf16x4*)&Bs[s][swz16(nn + 3, k4)] = p3;
    };

    const int NT = F_INT / 32;
    LOAD(0);
    WRITE(0);
    LOAD(32);
    BAR();

    for (int kt = 0; kt < NT; ++kt) {
        int cur = kt & 1;
        if (kt + 1 < NT) WRITE(cur ^ 1);
        if (kt + 2 < NT) LOAD((kt + 2) * 32);

        int kgl = (lane >> 4) * 8;
        bf16x8 af[4];
        #pragma unroll
        for (int mf = 0; mf < 4; ++mf)
            af[mf] = *(const bf16x8*)&As[cur][swz16(wm + mf * 16 + (lane & 15), kgl)];
        #pragma unroll
        for (int nf = 0; nf < 4; ++nf) {
            int rn = wn + nf * 16 + (lane & 15);
            bf16x8 bfr = *(const bf16x8*)&Bs[cur][swz16(rn, kgl)];
            #pragma unroll
            for (int mf = 0; mf < 4; ++mf)
                acc[mf][nf] = __builtin_amdgcn_mfma_f32_16x16x32_bf16(af[mf], bfr, acc[mf][nf], 0, 0, 0);
        }
        BAR();
    }

    #pragma unroll
    for (int mf = 0; mf < 4; ++mf) {
        #pragma unroll
        for (int nf = 0; nf < 4; ++nf) {
            int col = n0 + wn + nf * 16 + (lane & 15);
            #pragma unroll
            for (int r = 0; r < 4; ++r) {
                int grow = m0 + wm + mf * 16 + (lane >> 4) * 4 + r;
                if (grow < cnt)
                    P[(size_t)(base + grow) * D_HID + col] = (bf16)acc[mf][nf][r];
            }
        }
    }
}

// ---------------- combine ----------------
__global__ __launch_bounds__(256) void k_combine(const bf16* __restrict__ P,
                                                 const int* __restrict__ slots,
                                                 const float* __restrict__ tok_w,
                                                 float* __restrict__ out) {
    int t = blockIdx.x;
    int tid = threadIdx.x;
    __shared__ int ss[TOPK];
    __shared__ float ww[TOPK];
    if (tid < TOPK) { ss[tid] = slots[t * TOPK + tid]; ww[tid] = tok_w[t * TOPK + tid]; }
    __syncthreads();
    int c0 = tid * 8;
    float acc[8];
    {
        bf16x8 v0 = *(const bf16x8*)(P + (size_t)(SH_BASE + t) * D_HID + c0);
        bf16x8 v1 = *(const bf16x8*)(P + (size_t)(SH_BASE + T_TOK + t) * D_HID + c0);
        #pragma unroll
        for (int i = 0; i < 8; ++i) acc[i] = (float)v0[i] + (float)v1[i];
    }
    #pragma unroll
    for (int k = 0; k < TOPK; ++k) {
        bf16x8 v = *(const bf16x8*)(P + (size_t)ss[k] * D_HID + c0);
        float w = ww[k];
        #pragma unroll
        for (int i = 0; i < 8; ++i) acc[i] += w * (float)v[i];
    }
    float4 o0 = {acc[0], acc[1], acc[2], acc[3]};
    float4 o1 = {acc[4], acc[5], acc[6], acc[7]};
    *(float4*)(out + (size_t)t * D_HID + c0) = o0;
    *(float4*)(out + (size_t)t * D_HID + c0 + 4) = o1;
}

extern "C" void kernel_launch(void* const* d_in, const int* in_sizes, int n_in,
                              void* d_out, int out_size, void* d_ws, size_t ws_size,
                              hipStream_t stream) {
    const float* x  = (const float*)d_in[0];
    const float* wr = (const float*)d_in[1];
    const float* wg = (const float*)d_in[2];
    const float* wu = (const float*)d_in[3];
    const float* wd = (const float*)d_in[4];
    const float* sg = (const float*)d_in[5];
    const float* su = (const float*)d_in[6];
    const float* sd = (const float*)d_in[7];
    float* out = (float*)d_out;

    char* w = (char*)d_ws;
    int*   counts   = (int*)(w + 0);        // 32 ints
    int*   cursors  = (int*)(w + 256);      // 32 ints
    int*   offs     = (int*)(w + 512);      // 35 ints
    int*   tok_e    = (int*)(w + 8192);                 // 12288 ints
    float* tok_w    = (float*)(w + 8192 + 49152);       // 12288 floats
    int*   slots    = (int*)(w + 8192 + 2 * 49152);     // 12288 ints
    int*   rowtok   = (int*)(w + 8192 + 3 * 49152);     // 16384 ints
    bf16*  H        = (bf16*)(w + 262144);                                  // 16384 x 1408 bf16
    bf16*  P        = (bf16*)(w + 262144 + (size_t)ROWS_TOTAL * F_INT * 2); // 16384 x 2048 bf16
    bf16*  Xb       = (bf16*)(w + 262144 + (size_t)ROWS_TOTAL * F_INT * 2
                                        + (size_t)ROWS_TOTAL * D_HID * 2);  // 2048 x 2048 bf16

    hipMemsetAsync(counts, 0, 128, stream);
    k_xcvt<<<T_TOK * D_HID / 2048, 256, 0, stream>>>(x, Xb);
    k_router<<<T_TOK, 256, 0, stream>>>(x, wr, counts, tok_e, tok_w);
    k_plan<<<1, 64, 0, stream>>>(counts, offs, cursors);
    k_assign<<<T_TOK / 256, 256, 0, stream>>>(tok_e, offs, cursors, slots, rowtok);
    k_gateup<<<MAXT_GU * GU_NBN, 256, 0, stream>>>(
        Xb, wg, wu, sg, su, rowtok, counts, offs, H);
    k_down<<<MAXT_DN * (D_HID / 128), 256, 0, stream>>>(
        H, wd, sd, counts, offs, P);
    k_combine<<<T_TOK, 256, 0, stream>>>(P, slots, tok_w, out);
}